// Round 1
// baseline (2295.888 us; speedup 1.0000x reference)
//
#include <hip/hip_runtime.h>
#include <hip/hip_bf16.h>
#include <math.h>

#define NB 128
#define NT 20
#define NS 19
#define NR 49
#define NV 10000
#define NE 512
#define NH 512
#define NFD 512
#define NA 256
#define NG 2048
#define NKC 1536

// ------------------------------------------------------------------
// setup: Wcat = [W_ih | W_hh], bias = b_ih + b_hh, W_hT = W_h^T, hx=cx=0
// ------------------------------------------------------------------
__global__ __launch_bounds__(256) void k_setup(
    const float* __restrict__ W_ih, const float* __restrict__ W_hh,
    const float* __restrict__ b_ih, const float* __restrict__ b_hh,
    const float* __restrict__ W_h,
    float* __restrict__ Wcat, float* __restrict__ bias,
    float* __restrict__ W_hT, float* __restrict__ hx, float* __restrict__ cx)
{
    int idx = blockIdx.x * 256 + threadIdx.x;
    if (idx < NG * NKC) {
        int n = idx / NKC, k = idx % NKC;
        Wcat[idx] = (k < NE + NFD) ? W_ih[n * (NE + NFD) + k]
                                   : W_hh[n * NH + (k - NE - NFD)];
    }
    if (idx < NG) bias[idx] = b_ih[idx] + b_hh[idx];
    if (idx < NH * NA) {
        int k = idx / NA, a = idx % NA;
        W_hT[idx] = W_h[a * NH + k];
    }
    if (idx < NB * NH) { hx[idx] = 0.f; cx[idx] = 0.f; }
}

// ------------------------------------------------------------------
// attention: per-block batch element b.
//   h = hx @ W_h^T + b_h            (4-way K-split over thread quarter)
//   scores_r = tanh(h + fproj[b,r]) . v_w   (wave-parallel over r)
//   alpha = softmax_r(scores)               (v_b cancels)
//   lin[b] = [ emb[captions[b,t]] | alpha @ features[b] | hx[b] ]
// ------------------------------------------------------------------
__global__ __launch_bounds__(1024) void k_attn(
    const float* __restrict__ hx, const float* __restrict__ W_hT,
    const float* __restrict__ b_h, const float* __restrict__ fproj,
    const float* __restrict__ v_w, const float* __restrict__ features,
    const float* __restrict__ emb, const int* __restrict__ captions,
    float* __restrict__ lin, int t)
{
    int b = blockIdx.x;
    int tid = threadIdx.x;
    __shared__ float hxs[NH];
    __shared__ float part[4][NA];
    __shared__ float hatt[NA];
    __shared__ float salpha[64];

    if (tid < NH) hxs[tid] = hx[b * NH + tid];
    __syncthreads();

    {   // h = hx @ W_h^T  (thread (q,a): quarter-K partial dot)
        int a = tid & (NA - 1), q = tid >> 8;
        float p = 0.f;
        int k0 = q * (NH / 4);
        #pragma unroll 8
        for (int k = k0; k < k0 + NH / 4; ++k)
            p += hxs[k] * W_hT[k * NA + a];
        part[q][a] = p;
    }
    __syncthreads();
    if (tid < NA)
        hatt[tid] = part[0][tid] + part[1][tid] + part[2][tid] + part[3][tid] + b_h[tid];
    __syncthreads();

    {   // scores, 16 waves strided over r
        int wv = tid >> 6, lane = tid & 63;
        for (int r = wv; r < NR; r += 16) {
            float s = 0.f;
            const float* fp = fproj + (size_t)(b * NR + r) * NA;
            #pragma unroll
            for (int j = 0; j < 4; ++j) {
                int aa = lane + 64 * j;
                s += tanhf(hatt[aa] + fp[aa]) * v_w[aa];
            }
            #pragma unroll
            for (int off = 32; off; off >>= 1) s += __shfl_xor(s, off);
            if (lane == 0) salpha[r] = s;
        }
    }
    __syncthreads();

    if (tid < 64) {   // softmax over R=49 in wave 0
        float v = (tid < NR) ? salpha[tid] : -INFINITY;
        float m = v;
        #pragma unroll
        for (int off = 32; off; off >>= 1) m = fmaxf(m, __shfl_xor(m, off));
        float e = (tid < NR) ? expf(v - m) : 0.f;
        float ssum = e;
        #pragma unroll
        for (int off = 32; off; off >>= 1) ssum += __shfl_xor(ssum, off);
        if (tid < NR) salpha[tid] = e / ssum;
    }
    __syncthreads();

    if (tid < NH) {   // context + concatenated lstm input row
        float* lrow = lin + (size_t)b * NKC;
        lrow[tid] = emb[(size_t)captions[b * NT + t] * NE + tid];
        lrow[NE + NFD + tid] = hxs[tid];
        float c = 0.f;
        #pragma unroll 7
        for (int r = 0; r < NR; ++r)
            c += salpha[r] * features[(size_t)(b * NR + r) * NFD + tid];
        lrow[NE + tid] = c;
    }
}

// ------------------------------------------------------------------
// generic fp32 GEMM-NT:  C[M,N] = A[M,K] @ B[N,K]^T (+bias)
// tile 64x32, BK=16, 256 threads, 4x2 per thread, split-K via blockIdx.z
// ------------------------------------------------------------------
__global__ __launch_bounds__(256) void gemm_nt_f32(
    const float* __restrict__ Am, const float* __restrict__ Bm,
    const float* __restrict__ bias, float* __restrict__ Cm,
    int M, int N, int K, int kspan, int ldc)
{
    __shared__ float As[16][68];
    __shared__ float Bs[16][34];
    int tid = threadIdx.x;
    int m0 = blockIdx.x * 64;
    int n0 = blockIdx.y * 32;
    int k0 = blockIdx.z * kspan;
    int kend = min(K, k0 + kspan);
    int la_m = tid >> 2, la_k = (tid & 3) * 4;
    int lb_n = tid >> 3, lb_k = (tid & 7) * 2;
    int tm = (tid >> 4) * 4, tn = (tid & 15) * 2;
    const float* Ab = Am + (size_t)(m0 + la_m) * K;
    bool bval = (n0 + lb_n) < N;
    const float* Bb = Bm + (size_t)(n0 + lb_n) * K;
    float acc[4][2] = {};

    for (int k = k0; k < kend; k += 16) {
        float4 av = *(const float4*)(Ab + k + la_k);
        float2 bv = bval ? *(const float2*)(Bb + k + lb_k) : make_float2(0.f, 0.f);
        As[la_k + 0][la_m] = av.x; As[la_k + 1][la_m] = av.y;
        As[la_k + 2][la_m] = av.z; As[la_k + 3][la_m] = av.w;
        Bs[lb_k + 0][lb_n] = bv.x; Bs[lb_k + 1][lb_n] = bv.y;
        __syncthreads();
        #pragma unroll
        for (int kk = 0; kk < 16; ++kk) {
            float a0 = As[kk][tm], a1 = As[kk][tm + 1];
            float a2 = As[kk][tm + 2], a3 = As[kk][tm + 3];
            float b0 = Bs[kk][tn], b1 = Bs[kk][tn + 1];
            acc[0][0] += a0 * b0; acc[0][1] += a0 * b1;
            acc[1][0] += a1 * b0; acc[1][1] += a1 * b1;
            acc[2][0] += a2 * b0; acc[2][1] += a2 * b1;
            acc[3][0] += a3 * b0; acc[3][1] += a3 * b1;
        }
        __syncthreads();
    }

    Cm += (size_t)blockIdx.z * M * ldc;
    #pragma unroll
    for (int i = 0; i < 4; ++i) {
        int mm = m0 + tm + i;
        #pragma unroll
        for (int j = 0; j < 2; ++j) {
            int nn = n0 + tn + j;
            if (nn < N) {
                float v = acc[i][j];
                if (bias) v += bias[nn];
                Cm[(size_t)mm * ldc + nn] = v;
            }
        }
    }
}

// ------------------------------------------------------------------
// LSTM pointwise: reduce 2 K-partials, gate math, update hx/cx
// ------------------------------------------------------------------
__global__ __launch_bounds__(256) void k_lstm(
    const float* __restrict__ gpart, const float* __restrict__ bias,
    float* __restrict__ hx, float* __restrict__ cx)
{
    int idx = blockIdx.x * 256 + threadIdx.x;   // b*NH + h
    int b = idx >> 9, h = idx & (NH - 1);
    const float* g0 = gpart + (size_t)b * NG;
    const float* g1 = gpart + (size_t)NB * NG + (size_t)b * NG;
    float gi = bias[h]          + g0[h]          + g1[h];
    float gf = bias[NH + h]     + g0[NH + h]     + g1[NH + h];
    float gg = bias[2 * NH + h] + g0[2 * NH + h] + g1[2 * NH + h];
    float go = bias[3 * NH + h] + g0[3 * NH + h] + g1[3 * NH + h];
    float si = 1.f / (1.f + expf(-gi));
    float sf = 1.f / (1.f + expf(-gf));
    float so = 1.f / (1.f + expf(-go));
    float c  = sf * cx[idx] + si * tanhf(gg);
    float hn = so * tanhf(c);
    cx[idx] = c;
    hx[idx] = hn;
}

// ------------------------------------------------------------------
extern "C" void kernel_launch(void* const* d_in, const int* in_sizes, int n_in,
                              void* d_out, int out_size, void* d_ws, size_t ws_size,
                              hipStream_t stream)
{
    const float* features = (const float*)d_in[0];
    const int*   captions = (const int*)d_in[1];
    const float* emb      = (const float*)d_in[2];
    const float* W_h      = (const float*)d_in[3];
    const float* b_h      = (const float*)d_in[4];
    const float* W_f      = (const float*)d_in[5];
    const float* b_f      = (const float*)d_in[6];
    const float* v_w      = (const float*)d_in[7];
    // d_in[8] = v_b : cancels in softmax, unused
    const float* W_ih     = (const float*)d_in[9];
    const float* W_hh     = (const float*)d_in[10];
    const float* b_ih     = (const float*)d_in[11];
    const float* b_hh     = (const float*)d_in[12];
    const float* fc_W     = (const float*)d_in[13];
    const float* fc_b     = (const float*)d_in[14];
    float* out = (float*)d_out;

    float* w     = (float*)d_ws;
    float* Wcat  = w;                 // 3,145,728
    float* bias  = Wcat + 3145728;    // 2,048
    float* W_hT  = bias + 2048;       // 131,072
    float* fproj = W_hT + 131072;     // 1,605,632
    float* hx    = fproj + 1605632;   // 65,536
    float* cx    = hx + 65536;        // 65,536
    float* lin   = cx + 65536;        // 196,608
    float* gpart = lin + 196608;      // 524,288
    // total ~26.6 MB of d_ws

    k_setup<<<dim3((NG * NKC) / 256), 256, 0, stream>>>(
        W_ih, W_hh, b_ih, b_hh, W_h, Wcat, bias, W_hT, hx, cx);

    // f_proj = features @ W_f^T + b_f : (6272 x 256), K=512
    gemm_nt_f32<<<dim3(98, 8, 1), 256, 0, stream>>>(
        features, W_f, b_f, fproj, NB * NR, NA, NFD, NFD, NA);

    for (int t = 0; t < NS; ++t) {
        k_attn<<<dim3(NB), 1024, 0, stream>>>(
            hx, W_hT, b_h, fproj, v_w, features, emb, captions, lin, t);
        // gates partials: (128 x 2048), K=1536 split in 2
        gemm_nt_f32<<<dim3(2, 64, 2), 256, 0, stream>>>(
            lin, Wcat, nullptr, gpart, NB, NG, NKC, NKC / 2, NG);
        k_lstm<<<dim3((NB * NH) / 256), 256, 0, stream>>>(gpart, bias, hx, cx);
        // logits: (128 x 10000), K=512, direct into out[:, t, :]
        gemm_nt_f32<<<dim3(2, 313, 1), 256, 0, stream>>>(
            hx, fc_W, fc_b, out + (size_t)t * NV, NB, NV, NH, NH, NS * NV);
    }
}

// Round 2
// 671.289 us; speedup vs baseline: 3.4201x; 3.4201x over previous
//
#include <hip/hip_runtime.h>
#include <hip/hip_bf16.h>
#include <math.h>

#define NB 128
#define NT 20
#define NS 19
#define NR 49
#define NV 10000
#define NE 512
#define NH 512
#define NFD 512
#define NA 256
#define NG 2048
#define NKC 1536

typedef __bf16 bf16_t;
typedef bf16_t bf16x8 __attribute__((ext_vector_type(8)));
typedef float f32x4 __attribute__((ext_vector_type(4)));

// ------------------------------------------------------------------
// setup: bf16 weight copies, Wcat=[W_ih|W_hh], bias=b_ih+b_hh, W_hT,
// features->bf16, hx=cx=0, hxb=0
// ------------------------------------------------------------------
__global__ __launch_bounds__(256) void k_setup(
    const float* __restrict__ W_ih, const float* __restrict__ W_hh,
    const float* __restrict__ b_ih, const float* __restrict__ b_hh,
    const float* __restrict__ W_h, const float* __restrict__ fc_W,
    const float* __restrict__ W_f, const float* __restrict__ features,
    bf16_t* __restrict__ Wcatb, bf16_t* __restrict__ fcWb,
    bf16_t* __restrict__ Wfb, bf16_t* __restrict__ featb,
    float* __restrict__ bias, float* __restrict__ W_hT,
    float* __restrict__ hx, float* __restrict__ cx, bf16_t* __restrict__ hxb)
{
    int idx = blockIdx.x * 256 + threadIdx.x;
    if (idx < NV * NH) fcWb[idx] = (bf16_t)fc_W[idx];
    if (idx < NG * NKC) {
        int n = idx / NKC, k = idx % NKC;
        Wcatb[idx] = (bf16_t)((k < NE + NFD) ? W_ih[n * (NE + NFD) + k]
                                             : W_hh[n * NH + (k - NE - NFD)]);
    }
    if (idx < NB * NR * NFD) featb[idx] = (bf16_t)features[idx];
    if (idx < NA * NFD) Wfb[idx] = (bf16_t)W_f[idx];
    if (idx < NG) bias[idx] = b_ih[idx] + b_hh[idx];
    if (idx < NH * NA) {
        int k = idx / NA, a = idx % NA;
        W_hT[idx] = W_h[a * NH + k];
    }
    if (idx < NB * NH) { hx[idx] = 0.f; cx[idx] = 0.f; hxb[idx] = (bf16_t)0.f; }
}

// ------------------------------------------------------------------
// attention (fp32): per-block batch element b; writes lin row in bf16
// ------------------------------------------------------------------
__global__ __launch_bounds__(1024) void k_attn(
    const float* __restrict__ hx, const float* __restrict__ W_hT,
    const float* __restrict__ b_h, const float* __restrict__ fproj,
    const float* __restrict__ v_w, const float* __restrict__ features,
    const float* __restrict__ emb, const int* __restrict__ captions,
    bf16_t* __restrict__ lin, int t)
{
    int b = blockIdx.x;
    int tid = threadIdx.x;
    __shared__ float hxs[NH];
    __shared__ float part[4][NA];
    __shared__ float hatt[NA];
    __shared__ float salpha[64];

    if (tid < NH) hxs[tid] = hx[b * NH + tid];
    __syncthreads();

    {   // h = hx @ W_h^T  (thread (q,a): quarter-K partial dot)
        int a = tid & (NA - 1), q = tid >> 8;
        float p = 0.f;
        int k0 = q * (NH / 4);
        #pragma unroll 8
        for (int k = k0; k < k0 + NH / 4; ++k)
            p += hxs[k] * W_hT[k * NA + a];
        part[q][a] = p;
    }
    __syncthreads();
    if (tid < NA)
        hatt[tid] = part[0][tid] + part[1][tid] + part[2][tid] + part[3][tid] + b_h[tid];
    __syncthreads();

    {   // scores, 16 waves strided over r
        int wv = tid >> 6, lane = tid & 63;
        for (int r = wv; r < NR; r += 16) {
            float s = 0.f;
            const float* fp = fproj + (size_t)(b * NR + r) * NA;
            #pragma unroll
            for (int j = 0; j < 4; ++j) {
                int aa = lane + 64 * j;
                s += tanhf(hatt[aa] + fp[aa]) * v_w[aa];
            }
            #pragma unroll
            for (int off = 32; off; off >>= 1) s += __shfl_xor(s, off);
            if (lane == 0) salpha[r] = s;
        }
    }
    __syncthreads();

    if (tid < 64) {   // softmax over R=49 in wave 0
        float v = (tid < NR) ? salpha[tid] : -INFINITY;
        float m = v;
        #pragma unroll
        for (int off = 32; off; off >>= 1) m = fmaxf(m, __shfl_xor(m, off));
        float e = (tid < NR) ? expf(v - m) : 0.f;
        float ssum = e;
        #pragma unroll
        for (int off = 32; off; off >>= 1) ssum += __shfl_xor(ssum, off);
        if (tid < NR) salpha[tid] = e / ssum;
    }
    __syncthreads();

    if (tid < NH) {   // context + concatenated lstm input row (bf16)
        bf16_t* lrow = lin + (size_t)b * NKC;
        lrow[tid] = (bf16_t)emb[(size_t)captions[b * NT + t] * NE + tid];
        lrow[NE + NFD + tid] = (bf16_t)hxs[tid];
        float c = 0.f;
        #pragma unroll 7
        for (int r = 0; r < NR; ++r)
            c += salpha[r] * features[(size_t)(b * NR + r) * NFD + tid];
        lrow[NE + tid] = (bf16_t)c;
    }
}

// ------------------------------------------------------------------
// bf16 MFMA GEMM-NT:  C[M,N] = A[M,K] @ B[N,K]^T (+bias), fp32 out
// tile 64x64, BK=64, 256 thr = 4 waves (2x2), wave tile 32x32 (2x2 frags)
// LDS 16B-slot XOR swizzle (slot ^= row&7); reg-staged w/ next-tile prefetch
// split-K via blockIdx.z (kspan must be multiple of 64)
// ------------------------------------------------------------------
__global__ __launch_bounds__(256) void gemm_bf16_nt(
    const bf16_t* __restrict__ Am, const bf16_t* __restrict__ Bm,
    const float* __restrict__ bias, float* __restrict__ Cm,
    int M, int N, int K, int kspan, int ldc, long long zstride)
{
    __shared__ uint4 AsU[512];   // 64 rows x 8 slots (16B)
    __shared__ uint4 BsU[512];
    int tid = threadIdx.x;
    int m0 = blockIdx.x * 64, n0 = blockIdx.y * 64;
    int k0 = blockIdx.z * kspan;
    int nk = kspan >> 6;

    // staging map: thread t covers (row, slot) and (row+32, slot)
    int rowS = tid >> 3;
    int slotS = tid & 7;
    int wr0 = rowS * 8 + (slotS ^ (rowS & 7));
    int rowS2 = rowS + 32;
    int wr1 = rowS2 * 8 + (slotS ^ (rowS2 & 7));

    const uint4* pA = (const uint4*)(Am + (size_t)(m0 + rowS) * K + k0) + slotS;
    size_t aStep = (size_t)4 * K;             // +32 rows in uint4 units
    int nrow0 = n0 + rowS, nrow1 = n0 + rowS2;
    bool bv0 = nrow0 < N, bv1 = nrow1 < N;
    const uint4* pB0 = (const uint4*)(Bm + (size_t)nrow0 * K + k0) + slotS;
    const uint4* pB1 = (const uint4*)(Bm + (size_t)nrow1 * K + k0) + slotS;
    uint4 zz = make_uint4(0, 0, 0, 0);

    // fragment read indices (16B units), swizzled
    int w = tid >> 6, lane = tid & 63;
    int wm = w >> 1, wn = w & 1;
    int lr = lane & 15, lg = lane >> 4;
    int ra[2][2], rb[2][2];
    #pragma unroll
    for (int i = 0; i < 2; ++i)
        #pragma unroll
        for (int kk = 0; kk < 2; ++kk) {
            int rA = wm * 32 + i * 16 + lr;
            int rB = wn * 32 + i * 16 + lr;
            int s = kk * 4 + lg;
            ra[i][kk] = rA * 8 + (s ^ (rA & 7));
            rb[i][kk] = rB * 8 + (s ^ (rB & 7));
        }

    f32x4 acc00 = {}, acc01 = {}, acc10 = {}, acc11 = {};

    uint4 a0 = pA[0], a1 = pA[aStep];
    uint4 b0 = bv0 ? pB0[0] : zz;
    uint4 b1 = bv1 ? pB1[0] : zz;
    pA += 8; pB0 += 8; pB1 += 8;

    for (int kt = 0; kt < nk; ++kt) {
        __syncthreads();                       // previous compute done
        AsU[wr0] = a0; AsU[wr1] = a1;
        BsU[wr0] = b0; BsU[wr1] = b1;
        if (kt + 1 < nk) {                     // prefetch next tile
            a0 = pA[0]; a1 = pA[aStep];
            b0 = bv0 ? pB0[0] : zz;
            b1 = bv1 ? pB1[0] : zz;
            pA += 8; pB0 += 8; pB1 += 8;
        }
        __syncthreads();
        const bf16x8* Af = (const bf16x8*)AsU;
        const bf16x8* Bf = (const bf16x8*)BsU;
        #pragma unroll
        for (int kk = 0; kk < 2; ++kk) {
            bf16x8 fa0 = Af[ra[0][kk]], fa1 = Af[ra[1][kk]];
            bf16x8 fb0 = Bf[rb[0][kk]], fb1 = Bf[rb[1][kk]];
            acc00 = __builtin_amdgcn_mfma_f32_16x16x32_bf16(fa0, fb0, acc00, 0, 0, 0);
            acc01 = __builtin_amdgcn_mfma_f32_16x16x32_bf16(fa0, fb1, acc01, 0, 0, 0);
            acc10 = __builtin_amdgcn_mfma_f32_16x16x32_bf16(fa1, fb0, acc10, 0, 0, 0);
            acc11 = __builtin_amdgcn_mfma_f32_16x16x32_bf16(fa1, fb1, acc11, 0, 0, 0);
        }
    }

    Cm += (size_t)blockIdx.z * zstride;
    f32x4 av[2][2] = {{acc00, acc01}, {acc10, acc11}};
    #pragma unroll
    for (int i = 0; i < 2; ++i) {
        int mbase = m0 + wm * 32 + i * 16 + lg * 4;
        #pragma unroll
        for (int j = 0; j < 2; ++j) {
            int n = n0 + wn * 32 + j * 16 + lr;
            if (n < N) {
                float bz = bias ? bias[n] : 0.f;
                #pragma unroll
                for (int r = 0; r < 4; ++r)
                    Cm[(size_t)(mbase + r) * ldc + n] = av[i][j][r] + bz;
            }
        }
    }
}

// ------------------------------------------------------------------
// LSTM pointwise: reduce 4 K-partials, gate math, update hx/cx/hxb
// ------------------------------------------------------------------
__global__ __launch_bounds__(256) void k_lstm(
    const float* __restrict__ gpart, const float* __restrict__ bias,
    float* __restrict__ hx, float* __restrict__ cx, bf16_t* __restrict__ hxb)
{
    int idx = blockIdx.x * 256 + threadIdx.x;   // b*NH + h
    int b = idx >> 9, h = idx & (NH - 1);
    const float* g0 = gpart + (size_t)b * NG;
    float gi = bias[h],      gf = bias[NH + h];
    float gg = bias[2 * NH + h], go = bias[3 * NH + h];
    #pragma unroll
    for (int z = 0; z < 4; ++z) {
        const float* gz = g0 + (size_t)z * NB * NG;
        gi += gz[h];
        gf += gz[NH + h];
        gg += gz[2 * NH + h];
        go += gz[3 * NH + h];
    }
    float si = 1.f / (1.f + expf(-gi));
    float sf = 1.f / (1.f + expf(-gf));
    float so = 1.f / (1.f + expf(-go));
    float c  = sf * cx[idx] + si * tanhf(gg);
    float hn = so * tanhf(c);
    cx[idx] = c;
    hx[idx] = hn;
    hxb[idx] = (bf16_t)hn;
}

// ------------------------------------------------------------------
extern "C" void kernel_launch(void* const* d_in, const int* in_sizes, int n_in,
                              void* d_out, int out_size, void* d_ws, size_t ws_size,
                              hipStream_t stream)
{
    const float* features = (const float*)d_in[0];
    const int*   captions = (const int*)d_in[1];
    const float* emb      = (const float*)d_in[2];
    const float* W_h      = (const float*)d_in[3];
    const float* b_h      = (const float*)d_in[4];
    const float* W_f      = (const float*)d_in[5];
    const float* b_f      = (const float*)d_in[6];
    const float* v_w      = (const float*)d_in[7];
    // d_in[8] = v_b : cancels in softmax
    const float* W_ih     = (const float*)d_in[9];
    const float* W_hh     = (const float*)d_in[10];
    const float* b_ih     = (const float*)d_in[11];
    const float* b_hh     = (const float*)d_in[12];
    const float* fc_W     = (const float*)d_in[13];
    const float* fc_b     = (const float*)d_in[14];
    float* out = (float*)d_out;

    char* base = (char*)d_ws;
    bf16_t* Wcatb = (bf16_t*)base;  base += (size_t)NG * NKC * 2;       // 6,291,456
    bf16_t* fcWb  = (bf16_t*)base;  base += (size_t)NV * NH * 2;        // 10,240,000
    bf16_t* Wfb   = (bf16_t*)base;  base += (size_t)NA * NFD * 2;       // 262,144
    bf16_t* featb = (bf16_t*)base;  base += (size_t)NB * NR * NFD * 2;  // 6,422,528
    bf16_t* lin   = (bf16_t*)base;  base += (size_t)NB * NKC * 2;       // 393,216
    bf16_t* hxb   = (bf16_t*)base;  base += (size_t)NB * NH * 2;        // 131,072
    float* bias   = (float*)base;   base += (size_t)NG * 4;             // 8,192
    float* W_hT   = (float*)base;   base += (size_t)NH * NA * 4;        // 524,288
    float* fproj  = (float*)base;   base += (size_t)NB * NR * NA * 4;   // 6,422,528
    float* hx     = (float*)base;   base += (size_t)NB * NH * 4;        // 262,144
    float* cx     = (float*)base;   base += (size_t)NB * NH * 4;        // 262,144
    float* gpart  = (float*)base;   base += (size_t)4 * NB * NG * 4;    // 4,194,304
    // total ~35.4 MB

    k_setup<<<dim3((NV * NH + 255) / 256), 256, 0, stream>>>(
        W_ih, W_hh, b_ih, b_hh, W_h, fc_W, W_f, features,
        Wcatb, fcWb, Wfb, featb, bias, W_hT, hx, cx, hxb);

    // f_proj = features @ W_f^T + b_f : (6272 x 256), K=512
    gemm_bf16_nt<<<dim3(98, 4, 1), 256, 0, stream>>>(
        featb, Wfb, b_f, fproj, NB * NR, NA, NFD, NFD, NA, 0);

    for (int t = 0; t < NS; ++t) {
        k_attn<<<dim3(NB), 1024, 0, stream>>>(
            hx, W_hT, b_h, fproj, v_w, features, emb, captions, lin, t);
        // gates partials: (128 x 2048), K=1536 split in 4
        gemm_bf16_nt<<<dim3(2, 32, 4), 256, 0, stream>>>(
            lin, Wcatb, nullptr, gpart, NB, NG, NKC, NKC / 4, NG,
            (long long)NB * NG);
        k_lstm<<<dim3((NB * NH) / 256), 256, 0, stream>>>(gpart, bias, hx, cx, hxb);
        // logits: (128 x 10000), K=512, direct into out[:, t, :]
        gemm_bf16_nt<<<dim3(2, 157, 1), 256, 0, stream>>>(
            hxb, fcWb, fc_b, out + (size_t)t * NV, NB, NV, NH, NH, NS * NV, 0);
    }
}